// Round 17
// baseline (429.789 us; speedup 1.0000x reference)
//
#include <hip/hip_runtime.h>
#include <math.h>

#define D_MODEL 1024
#define D_STATE 16
#define D_CONV  4
#define D_INNER 2048
#define DT_RANK 64
#define BATCH   2
#define SEQLEN  1024
#define MROWS   2048
#define XDBL_LD 128
#define NCHUNK  32
#define CLEN    (SEQLEN / NCHUNK)   // 32
#define NCHG    8192                // 2 dirs * BATCH * D_INNER

typedef __attribute__((ext_vector_type(8))) short bf16x8;
typedef __attribute__((ext_vector_type(4))) float f32x4;

#define BARR() asm volatile("s_barrier" ::: "memory")
#define VMW(n) asm volatile("s_waitcnt vmcnt(" #n ")" ::: "memory")
#define LGKM(n) asm volatile("s_waitcnt lgkmcnt(" #n ")" ::: "memory")
#define SCHB() __builtin_amdgcn_sched_barrier(0)

static __device__ __forceinline__ float sigmoidf_(float x) {
    return 1.f / (1.f + __expf(-x));
}
static __device__ __forceinline__ unsigned short bf16rn(float f) {
    unsigned u = __float_as_uint(f);
    return (unsigned short)((u + 0x7FFFu + ((u >> 16) & 1u)) >> 16);
}
static __device__ __forceinline__ void hl_split(float f, unsigned short& h, unsigned short& l) {
    h = bf16rn(f);
    l = bf16rn(f - __uint_as_float((unsigned)h << 16));
}
static __device__ __forceinline__ float us2f(unsigned short u) {
    return __uint_as_float((unsigned)u << 16);
}

// ---------------------------------------------------------------------------
// Shared split worker: fp32 (R x C) -> bf16 (Rout x 2C) hi|lo.
// wlo=false: write only the hi half (for W operands of SEGS=2 GEMMs).
// ---------------------------------------------------------------------------
static __device__ __forceinline__
void split_block(const float* __restrict__ in, int R, int C, int ldin,
                 unsigned short* __restrict__ out, int Rout, bool flip,
                 int blk, int tid, bool wlo)
{
    int q = blk * 256 + tid;
    int qpr = C >> 2;
    int row = q / qpr;
    int c4 = (q - row * qpr) << 2;
    if (row >= Rout) return;
    unsigned short h[4] = {0, 0, 0, 0}, l[4] = {0, 0, 0, 0};
    if (row < R) {
        int sr = row;
        if (flip) { int b = row >> 10, t = row & 1023; sr = (b << 10) + (1023 - t); }
        float4 v = *(const float4*)(in + (size_t)sr * ldin + c4);
        float f[4] = {v.x, v.y, v.z, v.w};
        #pragma unroll
        for (int i = 0; i < 4; ++i) hl_split(f[i], h[i], l[i]);
    }
    size_t ob = (size_t)row * (2 * C);
    *(ushort4*)(out + ob + c4) = make_ushort4(h[0], h[1], h[2], h[3]);
    if (wlo)
        *(ushort4*)(out + ob + C + c4) = make_ushort4(l[0], l[1], l[2], l[3]);
}

// prep1: all pre-GEMM conversions in one launch. Win hi-only (SEGS=2).
__global__ __launch_bounds__(256)
void prep1_kernel(const float* __restrict__ x,
                  const float* __restrict__ Win0, const float* __restrict__ Win1,
                  const float* __restrict__ Wx0,  const float* __restrict__ Wx1,
                  const float* __restrict__ Wdt0, const float* __restrict__ Wdt1,
                  unsigned short* xc0,
                  unsigned short* Winb0, unsigned short* Winb1,
                  unsigned short* Wxb0, unsigned short* Wxb1,
                  unsigned short* Wdtb0, unsigned short* Wdtb1)
{
    int b = blockIdx.x, tid = threadIdx.x;
    if      (b < 2048)  split_block(x,    MROWS, D_MODEL, D_MODEL, xc0,  MROWS, false, b,        tid, true);
    else if (b < 6144)  split_block(Win0, 4096,  D_MODEL, D_MODEL, Winb0, 4096, false, b - 2048, tid, false);
    else if (b < 10240) split_block(Win1, 4096,  D_MODEL, D_MODEL, Winb1, 4096, false, b - 6144, tid, false);
    else if (b < 10496) split_block(Wx0,  96,    D_INNER, D_INNER, Wxb0,  128,  false, b - 10240, tid, true);
    else if (b < 10752) split_block(Wx1,  96,    D_INNER, D_INNER, Wxb1,  128,  false, b - 10496, tid, true);
    else if (b < 10880) split_block(Wdt0, D_INNER, DT_RANK, DT_RANK, Wdtb0, D_INNER, false, b - 10752, tid, true);
    else                split_block(Wdt1, D_INNER, DT_RANK, DT_RANK, Wdtb1, D_INNER, false, b - 10880, tid, true);
}

// ---------------------------------------------------------------------------
// 256x256 8-phase bf16 MFMA GEMM — r13 schedule, r15 col-major mapping,
// SEGS=2 (AhiWhi + AloWhi).
// ---------------------------------------------------------------------------
#define SWZ(row) (((row) >> 1) & 3)
#define RDA(p, kk, row) (*(const bf16x8*)&AS[p][kk][row][(fs ^ SWZ(row)) << 3])
#define RDB(p, kk, row) (*(const bf16x8*)&BS[p][kk][row][(fs ^ SWZ(row)) << 3])

#define MFMA16(ACCBASE, AF, BF) \
    _Pragma("unroll") for (int f = 0; f < 4; ++f) \
    _Pragma("unroll") for (int g = 0; g < 4; ++g) \
        acc[(ACCBASE) + f][g] = __builtin_amdgcn_mfma_f32_16x16x32_bf16(AF[f], BF[g], acc[(ACCBASE) + f][g], 0, 0, 0);

#define KTILE(MODE, kt) do { \
    const int p_ = (kt) & 1; \
    const int pn_ = ((kt) + 1) & 1; \
    { /* P1 */ \
        if (MODE < 2) stageA((kt) + 1, 1); \
        BARR(); \
        _Pragma("unroll") for (int f = 0; f < 4; ++f) { int rw = wm + 64 + f * 16 + fr; aFB[f] = RDA(p_, 0, rw); } \
        LGKM(4); SCHB(); \
        __builtin_amdgcn_s_setprio(1); \
        MFMA16(0, aFA, bFA) \
        __builtin_amdgcn_s_setprio(0); \
    } \
    { /* P2 */ \
        if (MODE == 0) stageB((kt) + 2, 0); \
        BARR(); \
        _Pragma("unroll") for (int f = 0; f < 4; ++f) { int rw = wm + f * 16 + fr; aFA[f] = RDA(p_, 1, rw); } \
        _Pragma("unroll") for (int g = 0; g < 4; ++g) { int rw = wn + g * 16 + fr; bFB[g] = RDB(p_, 1, rw); } \
        LGKM(8); SCHB(); \
        __builtin_amdgcn_s_setprio(1); \
        MFMA16(4, aFB, bFA) \
        __builtin_amdgcn_s_setprio(0); \
    } \
    { /* P3 */ \
        if (MODE == 0) stageA((kt) + 2, 0); \
        BARR(); \
        _Pragma("unroll") for (int f = 0; f < 4; ++f) { int rw = wm + 64 + f * 16 + fr; aFB[f] = RDA(p_, 1, rw); } \
        LGKM(4); SCHB(); \
        __builtin_amdgcn_s_setprio(1); \
        MFMA16(0, aFA, bFB) \
        __builtin_amdgcn_s_setprio(0); \
    } \
    { /* P4 */ \
        if (MODE == 0) { VMW(4); } else if (MODE == 1) { VMW(0); } \
        if (MODE == 0) stageB((kt) + 2, 1); \
        BARR(); \
        if (MODE < 2) { \
            _Pragma("unroll") for (int f = 0; f < 4; ++f) { int rw = wm + f * 16 + fr; aFA[f] = RDA(pn_, 0, rw); } \
            _Pragma("unroll") for (int g = 0; g < 4; ++g) { int rw = wn + g * 16 + fr; bFA[g] = RDB(pn_, 0, rw); } \
            LGKM(8); \
        } else { LGKM(0); } \
        SCHB(); \
        __builtin_amdgcn_s_setprio(1); \
        MFMA16(4, aFB, bFB) \
        __builtin_amdgcn_s_setprio(0); \
    } \
} while (0)

template<int KTS, bool DUALN, int SEGS>
__global__ __launch_bounds__(512, 1)
void gemm256(const unsigned short* __restrict__ A0,
             const unsigned short* __restrict__ A1,
             const unsigned short* __restrict__ W0,
             const unsigned short* __restrict__ W1,
             const float* __restrict__ bias0,
             const float* __restrict__ bias1,
             float* __restrict__ C0, float* __restrict__ C1,
             int ldc, int N, int K)
{
    __shared__ unsigned short AS[2][2][256][32];
    __shared__ unsigned short BS[2][2][256][32];

    const int tid = threadIdx.x;
    const int lane = tid & 63;
    const int wid = tid >> 6;

    const int zdir = blockIdx.z;

    const int nbx = gridDim.x;
    const int nby = gridDim.y;
    const int nwg = nbx * nby;
    int bid = blockIdx.y * nbx + blockIdx.x;
    int q8 = nwg >> 3;
    int swz = (bid & 7) * q8 + (bid >> 3);
    const int bm = (swz % nby) * 256;
    const int bn = (swz / nby) * 256;

    int dn, bnn;
    if (DUALN) { dn = (bn >= (N >> 1)) ? 1 : 0; bnn = bn - dn * (N >> 1); }
    else       { dn = zdir; bnn = bn; }
    const unsigned short* A = (DUALN || dn == 0) ? A0 : A1;
    const unsigned short* W = dn ? W1 : W0;

    const int ldg = 2 * K;
    constexpr int NT = SEGS * KTS;

    const int wm = (wid >> 2) * 128;
    const int wn = (wid & 3) * 64;
    const int fr = lane & 15;
    const int fs = lane >> 4;

    f32x4 acc[8][4];
    #pragma unroll
    for (int i = 0; i < 8; ++i)
        #pragma unroll
        for (int j = 0; j < 4; ++j) {
            f32x4 zv = {0.f, 0.f, 0.f, 0.f};
            acc[i][j] = zv;
        }

    auto koffA = [&](int t) { unsigned tu = (unsigned)t; unsigned sg = tu / KTS;
                              unsigned w = tu - sg * KTS;
                              return (int)((sg == 1 ? (unsigned)K : 0u) + w * 64); };
    auto koffB = [&](int t) { unsigned tu = (unsigned)t; unsigned sg = tu / KTS;
                              unsigned w = tu - sg * KTS;
                              return (int)((sg == 2 ? (unsigned)K : 0u) + w * 64); };

    auto stageA = [&](int t, int kk) {
        int ko = koffA(t) + kk * 32;
        unsigned short* dst = &AS[t & 1][kk][0][0];
        #pragma unroll
        for (int i = 0; i < 2; ++i) {
            int s = i * 512 + tid;
            int row = s >> 2, sl = s & 3, lsl = sl ^ SWZ(row);
            const unsigned short* src = A + (size_t)(bm + row) * ldg + ko + lsl * 8;
            __builtin_amdgcn_global_load_lds(
                (const __attribute__((address_space(1))) void*)src,
                (__attribute__((address_space(3))) void*)(dst + s * 8), 16, 0, 0);
        }
    };
    auto stageB = [&](int t, int kk) {
        int ko = koffB(t) + kk * 32;
        unsigned short* dst = &BS[t & 1][kk][0][0];
        #pragma unroll
        for (int i = 0; i < 2; ++i) {
            int s = i * 512 + tid;
            int row = s >> 2, sl = s & 3, lsl = sl ^ SWZ(row);
            const unsigned short* src = W + (size_t)(bnn + row) * ldg + ko + lsl * 8;
            __builtin_amdgcn_global_load_lds(
                (const __attribute__((address_space(1))) void*)src,
                (__attribute__((address_space(3))) void*)(dst + s * 8), 16, 0, 0);
        }
    };

    stageB(0, 0); stageA(0, 0); stageB(0, 1); stageA(0, 1);
    stageB(1, 0); stageA(1, 0); stageB(1, 1);
    VMW(6);
    BARR();

    bf16x8 aFA[4], aFB[4], bFA[4], bFB[4];
    #pragma unroll
    for (int f = 0; f < 4; ++f) { int rw = wm + f * 16 + fr; aFA[f] = RDA(0, 0, rw); }
    #pragma unroll
    for (int g = 0; g < 4; ++g) { int rw = wn + g * 16 + fr; bFA[g] = RDB(0, 0, rw); }

    #pragma unroll 1
    for (int kt = 0; kt < NT - 2; ++kt) KTILE(0, kt);
    KTILE(1, NT - 2);
    KTILE(2, NT - 1);

    const float* bias = dn ? bias1 : bias0;
    float* C = dn ? C1 : C0;
    #pragma unroll
    for (int i = 0; i < 8; ++i)
        #pragma unroll
        for (int j = 0; j < 4; ++j) {
            int coln = bnn + wn + j * 16 + fr;
            float bv = bias ? bias[coln] : 0.f;
            #pragma unroll
            for (int r = 0; r < 4; ++r) {
                int rowm = bm + wm + i * 16 + fs * 4 + r;
                float v = acc[i][j][r] + bv;
                int crow = rowm;
                if (DUALN && dn) { int bb = rowm >> 10, t = rowm & 1023; crow = (bb << 10) + 1023 - t; }
                C[(size_t)crow * ldc + coln] = v;
            }
        }
}

// ---------------------------------------------------------------------------
// 128x128 2-phase pipelined GEMM (r14-validated schedule), SEGS=2, direct
// epilogues. EPI=0: fp32 C + bias. EPI=2: TMPB (bias + dir-flip + hi/lo bf16
// into tmpb at column offset dir*1024).
// ---------------------------------------------------------------------------
#define MF16(AF, BF) \
    _Pragma("unroll") for (int f = 0; f < 4; ++f) \
    _Pragma("unroll") for (int g = 0; g < 4; ++g) \
        acc[f][g] = __builtin_amdgcn_mfma_f32_16x16x32_bf16(AF[f], BF[g], acc[f][g], 0, 0, 0);

#define KT128(MODE, kt) do { \
    const int p_ = (kt) & 1; \
    const int pn_ = ((kt) + 1) & 1; \
    { /* P1: MFMA kk0 (set A); prefetch kk1 (set B); stage kt+1 kk0 */ \
        if (MODE == 0) { stageA((kt) + 1, 0); stageB((kt) + 1, 0); VMW(4); } \
        else { VMW(0); } \
        BARR(); \
        _Pragma("unroll") for (int f = 0; f < 4; ++f) { int rw = wm + f * 16 + fr; aFB[f] = RDA(p_, 1, rw); } \
        _Pragma("unroll") for (int g = 0; g < 4; ++g) { int rw = wn + g * 16 + fr; bFB[g] = RDB(p_, 1, rw); } \
        LGKM(8); SCHB(); \
        __builtin_amdgcn_s_setprio(1); \
        MF16(aFA, bFA) \
        __builtin_amdgcn_s_setprio(0); \
    } \
    { /* P2: MFMA kk1 (set B); prefetch next kk0 (set A); stage kt+1 kk1 */ \
        if (MODE == 0) { \
            stageA((kt) + 1, 1); stageB((kt) + 1, 1); VMW(4); BARR(); \
            _Pragma("unroll") for (int f = 0; f < 4; ++f) { int rw = wm + f * 16 + fr; aFA[f] = RDA(pn_, 0, rw); } \
            _Pragma("unroll") for (int g = 0; g < 4; ++g) { int rw = wn + g * 16 + fr; bFA[g] = RDB(pn_, 0, rw); } \
            LGKM(8); \
        } else { LGKM(0); } \
        SCHB(); \
        __builtin_amdgcn_s_setprio(1); \
        MF16(aFB, bFB) \
        __builtin_amdgcn_s_setprio(0); \
    } \
} while (0)

template<int EPI, int KTS, int SEGS>
__global__ __launch_bounds__(256, 2)
void gemm128p(const unsigned short* __restrict__ A0,
              const unsigned short* __restrict__ A1,
              const unsigned short* __restrict__ W0,
              const unsigned short* __restrict__ W1,
              const float* __restrict__ bias0,
              const float* __restrict__ bias1,
              float* __restrict__ C0f,
              unsigned short* __restrict__ Tb,
              int ldc, int K)
{
    __shared__ unsigned short AS[2][2][128][32];
    __shared__ unsigned short BS[2][2][128][32];

    const int tid = threadIdx.x;
    const int lane = tid & 63;
    const int wid = tid >> 6;

    const int dir = blockIdx.z;
    const unsigned short* A = dir ? A1 : A0;
    const unsigned short* W = dir ? W1 : W0;

    const int nbx = gridDim.x;
    const int nwg = nbx * gridDim.y;
    int bid = blockIdx.y * nbx + blockIdx.x;
    int q8 = nwg >> 3;
    int swz = (bid & 7) * q8 + (bid >> 3);
    const int bm = (swz / nbx) * 128;
    const int bn = (swz % nbx) * 128;

    const int ldg = 2 * K;
    constexpr int NT = SEGS * KTS;

    const int wm = (wid >> 1) * 64;
    const int wn = (wid & 1) * 64;
    const int fr = lane & 15;
    const int fs = lane >> 4;

    f32x4 acc[4][4];
    #pragma unroll
    for (int i = 0; i < 4; ++i)
        #pragma unroll
        for (int j = 0; j < 4; ++j) {
            f32x4 zv = {0.f, 0.f, 0.f, 0.f};
            acc[i][j] = zv;
        }

    auto koffA = [&](int t) { unsigned tu = (unsigned)t; unsigned sg = tu / KTS;
                              unsigned w = tu - sg * KTS;
                              return (int)((sg == 1 ? (unsigned)K : 0u) + w * 64); };
    auto koffB = [&](int t) { unsigned tu = (unsigned)t; unsigned sg = tu / KTS;
                              unsigned w = tu - sg * KTS;
                              return (int)((sg == 2 ? (unsigned)K : 0u) + w * 64); };

    auto stageA = [&](int t, int kk) {
        int ko = koffA(t) + kk * 32;
        unsigned short* dst = &AS[t & 1][kk][0][0];
        #pragma unroll
        for (int i = 0; i < 2; ++i) {
            int s = i * 256 + tid;
            int row = s >> 2, sl = s & 3, lsl = sl ^ SWZ(row);
            const unsigned short* src = A + (size_t)(bm + row) * ldg + ko + lsl * 8;
            __builtin_amdgcn_global_load_lds(
                (const __attribute__((address_space(1))) void*)src,
                (__attribute__((address_space(3))) void*)(dst + s * 8), 16, 0, 0);
        }
    };
    auto stageB = [&](int t, int kk) {
        int ko = koffB(t) + kk * 32;
        unsigned short* dst = &BS[t & 1][kk][0][0];
        #pragma unroll
        for (int i = 0; i < 2; ++i) {
            int s = i * 256 + tid;
            int row = s >> 2, sl = s & 3, lsl = sl ^ SWZ(row);
            const unsigned short* src = W + (size_t)(bn + row) * ldg + ko + lsl * 8;
            __builtin_amdgcn_global_load_lds(
                (const __attribute__((address_space(1))) void*)src,
                (__attribute__((address_space(3))) void*)(dst + s * 8), 16, 0, 0);
        }
    };

    // prologue: stage tile 0 fully; wait kk0 pair; publish; preload kk0 regs
    stageA(0, 0); stageB(0, 0); stageA(0, 1); stageB(0, 1);
    VMW(4);
    BARR();

    bf16x8 aFA[4], aFB[4], bFA[4], bFB[4];
    #pragma unroll
    for (int f = 0; f < 4; ++f) { int rw = wm + f * 16 + fr; aFA[f] = RDA(0, 0, rw); }
    #pragma unroll
    for (int g = 0; g < 4; ++g) { int rw = wn + g * 16 + fr; bFA[g] = RDB(0, 0, rw); }

    #pragma unroll 1
    for (int kt = 0; kt < NT - 1; ++kt) KT128(0, kt);
    KT128(2, NT - 1);

    const float* bias = dir ? bias1 : bias0;
    if (EPI == 0) {
        float* C = C0f;
        #pragma unroll
        for (int i = 0; i < 4; ++i)
            #pragma unroll
            for (int j = 0; j < 4; ++j) {
                int coln = bn + wn + j * 16 + fr;
                float bv = bias ? bias[coln] : 0.f;
                #pragma unroll
                for (int r = 0; r < 4; ++r) {
                    int rowm = bm + wm + i * 16 + fs * 4 + r;
                    C[(size_t)rowm * ldc + coln] = acc[i][j][r] + bv;
                }
            }
    } else {
        const int colofs = dir ? D_MODEL : 0;
        #pragma unroll
        for (int i = 0; i < 4; ++i)
            #pragma unroll
            for (int j = 0; j < 4; ++j) {
                int coln = bn + wn + j * 16 + fr;
                float bv = bias[coln];
                #pragma unroll
                for (int r = 0; r < 4; ++r) {
                    int rowm = bm + wm + i * 16 + fs * 4 + r;
                    float v = acc[i][j][r] + bv;
                    int orow = rowm;
                    if (dir) { int bb = rowm >> 10, t = rowm & 1023; orow = (bb << 10) + 1023 - t; }
                    unsigned short h, l;
                    hl_split(v, h, l);
                    Tb[(size_t)orow * 4096 + colofs + coln] = h;
                    Tb[(size_t)orow * 4096 + 2048 + colofs + coln] = l;
                }
            }
    }
}

// ---------------------------------------------------------------------------
// 128x128 bf16x3 MFMA GEMM (2-barrier) for small shapes (xproj/dt) — 3-seg.
// ---------------------------------------------------------------------------
template<int ACT, bool PART>
__global__ __launch_bounds__(256)
void gemm_mfma(const unsigned short* __restrict__ A0,
               const unsigned short* __restrict__ A1,
               const unsigned short* __restrict__ W0,
               const unsigned short* __restrict__ W1,
               const float* __restrict__ bias0,
               const float* __restrict__ bias1,
               float* __restrict__ C0, float* __restrict__ C1,
               float* __restrict__ part,
               int ldc, int N, int K, int nks)
{
    __shared__ __align__(16) unsigned short As[128 * 32];
    __shared__ __align__(16) unsigned short Bs[128 * 32];

    const int tid = threadIdx.x;
    const int lane = tid & 63;
    const int wid = tid >> 6;

    const int z = blockIdx.z;
    const int dir = z / nks;
    const int ks = z - dir * nks;
    const unsigned short* A = dir ? A1 : A0;
    const unsigned short* W = dir ? W1 : W0;

    const int nbx = gridDim.x;
    const int nwg = nbx * gridDim.y;
    int bid = blockIdx.y * nbx + blockIdx.x;
    int q8 = nwg >> 3;
    int swz = (nwg >= 8) ? (bid & 7) * q8 + (bid >> 3) : bid;
    const int bm = (swz / nbx) * 128;
    const int bn = (swz % nbx) * 128;

    const int ldg = 2 * K;
    const int Kc = K / nks;
    const int kbase = ks * Kc;

    f32x4 acc[4][4];
    #pragma unroll
    for (int i = 0; i < 4; ++i)
        #pragma unroll
        for (int j = 0; j < 4; ++j) {
            f32x4 zv = {0.f, 0.f, 0.f, 0.f};
            acc[i][j] = zv;
        }

    const int r0 = tid >> 2;
    const int k0s = (tid & 3) ^ ((r0 >> 1) & 3);
    const int r1 = (256 + tid) >> 2;
    const int k1s = (tid & 3) ^ ((r1 >> 1) & 3);

    unsigned short* As_w0 = &As[(wid << 6) * 8];
    unsigned short* As_w1 = &As[(256 + (wid << 6)) * 8];
    unsigned short* Bs_w0 = &Bs[(wid << 6) * 8];
    unsigned short* Bs_w1 = &Bs[(256 + (wid << 6)) * 8];

    const int wm = (wid >> 1) * 64;
    const int wn = (wid & 1) * 64;
    const int fr = lane & 15;
    const int fs = lane >> 4;

    const int KS = Kc >> 5;
    #pragma unroll 1
    for (int seg = 0; seg < 3; ++seg) {
        const int aoff = ((seg == 1) ? K : 0) + kbase;
        const int boff = ((seg == 2) ? K : 0) + kbase;
        #pragma unroll 1
        for (int kt = 0; kt < KS; ++kt) {
            const int kk = kt << 5;
            const unsigned short* ga0 = A + (size_t)(bm + r0) * ldg + aoff + kk + k0s * 8;
            const unsigned short* ga1 = A + (size_t)(bm + r1) * ldg + aoff + kk + k1s * 8;
            const unsigned short* gw0 = W + (size_t)(bn + r0) * ldg + boff + kk + k0s * 8;
            const unsigned short* gw1 = W + (size_t)(bn + r1) * ldg + boff + kk + k1s * 8;
            __builtin_amdgcn_global_load_lds(
                (const __attribute__((address_space(1))) void*)ga0,
                (__attribute__((address_space(3))) void*)As_w0, 16, 0, 0);
            __builtin_amdgcn_global_load_lds(
                (const __attribute__((address_space(1))) void*)ga1,
                (__attribute__((address_space(3))) void*)As_w1, 16, 0, 0);
            __builtin_amdgcn_global_load_lds(
                (const __attribute__((address_space(1))) void*)gw0,
                (__attribute__((address_space(3))) void*)Bs_w0, 16, 0, 0);
            __builtin_amdgcn_global_load_lds(
                (const __attribute__((address_space(1))) void*)gw1,
                (__attribute__((address_space(3))) void*)Bs_w1, 16, 0, 0);
            __syncthreads();

            bf16x8 aF[4], bF[4];
            #pragma unroll
            for (int f = 0; f < 4; ++f) {
                int ra = wm + f * 16 + fr;
                int sa = fs ^ ((ra >> 1) & 3);
                aF[f] = *(const bf16x8*)&As[ra * 32 + sa * 8];
                int rb = wn + f * 16 + fr;
                int sb = fs ^ ((rb >> 1) & 3);
                bF[f] = *(const bf16x8*)&Bs[rb * 32 + sb * 8];
            }
            #pragma unroll
            for (int i = 0; i < 4; ++i)
                #pragma unroll
                for (int j = 0; j < 4; ++j)
                    acc[i][j] = __builtin_amdgcn_mfma_f32_16x16x32_bf16(
                        aF[i], bF[j], acc[i][j], 0, 0, 0);
            __syncthreads();
        }
    }

    if (PART) {
        float* P = part + (size_t)z * ((size_t)MROWS * N);
        #pragma unroll
        for (int i = 0; i < 4; ++i)
            #pragma unroll
            for (int j = 0; j < 4; ++j) {
                int coln = bn + wn + j * 16 + fr;
                #pragma unroll
                for (int r = 0; r < 4; ++r) {
                    int rowm = bm + wm + i * 16 + fs * 4 + r;
                    P[(size_t)rowm * N + coln] = acc[i][j][r];
                }
            }
    } else {
        const float* bias = dir ? bias1 : bias0;
        float* C = dir ? C1 : C0;
        #pragma unroll
        for (int i = 0; i < 4; ++i)
            #pragma unroll
            for (int j = 0; j < 4; ++j) {
                int coln = bn + wn + j * 16 + fr;
                float bv = bias ? bias[coln] : 0.f;
                #pragma unroll
                for (int r = 0; r < 4; ++r) {
                    int rowm = bm + wm + i * 16 + fs * 4 + r;
                    float v = acc[i][j][r] + bv;
                    if (ACT == 1) v = (v > 20.f) ? v : log1pf(__expf(v));
                    C[(size_t)rowm * ldc + coln] = v;
                }
            }
    }
}

// ---------------------------------------------------------------------------
// Split-K reduce for xproj (z-batched over dir).
// ---------------------------------------------------------------------------
__global__ __launch_bounds__(256)
void reduce_xdbl_k(const float* __restrict__ part,
                   float* __restrict__ xdbl0, float* __restrict__ xdbl1,
                   unsigned short* __restrict__ dtb0, unsigned short* __restrict__ dtb1)
{
    const int dz = blockIdx.z;
    const float* P = part + (size_t)dz * 16 * MROWS * XDBL_LD;
    float* xdbl = dz ? xdbl1 : xdbl0;
    unsigned short* dtb = dz ? dtb1 : dtb0;
    int i = blockIdx.x * 256 + threadIdx.x;
    int row = i >> 5;
    int c4 = (i & 31) << 2;
    float4 s = make_float4(0.f, 0.f, 0.f, 0.f);
    #pragma unroll
    for (int k = 0; k < 16; ++k) {
        float4 v = *(const float4*)(P + (size_t)k * MROWS * XDBL_LD + (size_t)row * XDBL_LD + c4);
        s.x += v.x; s.y += v.y; s.z += v.z; s.w += v.w;
    }
    *(float4*)(xdbl + (size_t)row * XDBL_LD + c4) = s;
    if (c4 < DT_RANK) {
        float f[4] = {s.x, s.y, s.z, s.w};
        unsigned short h[4], l[4];
        #pragma unroll
        for (int j = 0; j < 4; ++j) hl_split(f[j], h[j], l[j]);
        *(ushort4*)(dtb + (size_t)row * (2 * DT_RANK) + c4) = make_ushort4(h[0], h[1], h[2], h[3]);
        *(ushort4*)(dtb + (size_t)row * (2 * DT_RANK) + DT_RANK + c4) = make_ushort4(l[0], l[1], l[2], l[3]);
    }
}

// pW split (hi-only; runs after out-proj frees ub[1]).
__global__ __launch_bounds__(256)
void pwsplit_kernel(const float* __restrict__ projW, unsigned short* __restrict__ pWb)
{
    split_block(projW, D_MODEL, 2 * D_MODEL, 2 * D_MODEL, pWb, D_MODEL, false,
                blockIdx.x, threadIdx.x, false);
}

// ---------------------------------------------------------------------------
// conv+prep2: z=0/1 -> causal conv + SiLU -> ub hi/lo; z=2 -> Wout hi-only.
// ---------------------------------------------------------------------------
__global__ __launch_bounds__(256)
void conv_prep_kernel(const float* __restrict__ xz0, const float* __restrict__ xz1,
                      const float* __restrict__ cw0, const float* __restrict__ cw1,
                      const float* __restrict__ cb0, const float* __restrict__ cb1,
                      unsigned short* __restrict__ ub0, unsigned short* __restrict__ ub1,
                      const float* __restrict__ Wout0, const float* __restrict__ Wout1,
                      unsigned short* __restrict__ Woutb0, unsigned short* __restrict__ Woutb1)
{
    const int dz = blockIdx.z;
    const int tid = threadIdx.x;
    if (dz == 2) {
        int b = blockIdx.x;
        if (b < 2048) split_block(Wout0, D_MODEL, D_INNER, D_INNER, Woutb0, D_MODEL, false, b, tid, false);
        else if (b < 4096) split_block(Wout1, D_MODEL, D_INNER, D_INNER, Woutb1, D_MODEL, false, b - 2048, tid, false);
        return;
    }
    const float* xz = dz ? xz1 : xz0;
    const float* convw = dz ? cw1 : cw0;
    const float* convb = dz ? cb1 : cb0;
    unsigned short* ub = dz ? ub1 : ub0;
    int idx = blockIdx.x * 256 + tid;
    int d = idx % D_INNER;
    int r = idx / D_INNER;
    int t = r % SEQLEN;
    float acc = convb[d];
    #pragma unroll
    for (int k = 0; k < D_CONV; ++k) {
        int back = D_CONV - 1 - k;
        if (t - back >= 0)
            acc += xz[(size_t)(r - back) * (2 * D_INNER) + d] * convw[d * D_CONV + k];
    }
    float v = acc * sigmoidf_(acc);
    unsigned short h, l;
    hl_split(v, h, l);
    ub[(size_t)r * (2 * D_INNER) + d] = h;
    ub[(size_t)r * (2 * D_INNER) + D_INNER + d] = l;
}

// ---------------------------------------------------------------------------
// Chunked selective scan, thread-per-channel (16 states in registers).
// ---------------------------------------------------------------------------
__global__ __launch_bounds__(256)
void scan_phase1(const float* __restrict__ delta0, const float* __restrict__ delta1,
                 const unsigned short* __restrict__ ub0, const unsigned short* __restrict__ ub1,
                 const float* __restrict__ xdbl0, const float* __restrict__ xdbl1,
                 const float* __restrict__ Alog0, const float* __restrict__ Alog1,
                 float* __restrict__ aprod, float* __restrict__ hfin)
{
    const int gid = blockIdx.x * 256 + threadIdx.x;
    const int chg = gid & (NCHG - 1);
    const int chunk = gid >> 13;
    const int dir = chg >> 12;
    const int bd = chg & 4095;
    const int b = bd >> 11, d = bd & 2047;
    const float* delta = dir ? delta1 : delta0;
    const unsigned short* ub = dir ? ub1 : ub0;
    const float* xdbl = dir ? xdbl1 : xdbl0;
    const float* Alog = dir ? Alog1 : Alog0;

    float Av[16], h[16], ap[16];
    #pragma unroll
    for (int n = 0; n < 16; ++n) {
        Av[n] = -__expf(Alog[d * D_STATE + n]);
        h[n] = 0.f; ap[n] = 1.f;
    }
    const int t0 = chunk * CLEN;
    for (int t = t0; t < t0 + CLEN; ++t) {
        const size_t r = (size_t)b * SEQLEN + t;
        float dlt = delta[r * D_INNER + d];
        float uu = us2f(ub[r * 4096 + d]) + us2f(ub[r * 4096 + 2048 + d]);
        float du = dlt * uu;
        float4 bq[4];
        #pragma unroll
        for (int q = 0; q < 4; ++q)
            bq[q] = *(const float4*)(xdbl + r * XDBL_LD + DT_RANK + q * 4);
        #pragma unroll
        for (int n = 0; n < 16; ++n) {
            float Bv = ((const float*)&bq[n >> 2])[n & 3];
            float dA = __expf(dlt * Av[n]);
            h[n] = h[n] * dA + du * Bv;
            ap[n] *= dA;
        }
    }
    float* pa = aprod + (size_t)chunk * (NCHG * 16) + (size_t)chg * 16;
    float* pf = hfin  + (size_t)chunk * (NCHG * 16) + (size_t)chg * 16;
    #pragma unroll
    for (int q = 0; q < 4; ++q) {
        *(float4*)(pa + q * 4) = make_float4(ap[q*4], ap[q*4+1], ap[q*4+2], ap[q*4+3]);
        *(float4*)(pf + q * 4) = make_float4(h[q*4], h[q*4+1], h[q*4+2], h[q*4+3]);
    }
}

__global__ __launch_bounds__(256)
void scan_phase2(float* __restrict__ aprod /* in: A, out: hin */,
                 const float* __restrict__ hfin)
{
    const int gid = blockIdx.x * 256 + threadIdx.x;
    float h = 0.f;
    for (int c = 0; c < NCHUNK; ++c) {
        const size_t idx = (size_t)c * (NCHG * 16) + gid;
        float a = aprod[idx];
        float f = hfin[idx];
        aprod[idx] = h;
        h = a * h + f;
    }
}

__global__ __launch_bounds__(256)
void scan_phase3(const float* __restrict__ delta0, const float* __restrict__ delta1,
                 unsigned short* __restrict__ ub0, unsigned short* __restrict__ ub1,
                 const float* __restrict__ xdbl0, const float* __restrict__ xdbl1,
                 const float* __restrict__ Alog0, const float* __restrict__ Alog1,
                 const float* __restrict__ Dsk0, const float* __restrict__ Dsk1,
                 const float* __restrict__ xz0, const float* __restrict__ xz1,
                 const float* __restrict__ hin)
{
    const int gid = blockIdx.x * 256 + threadIdx.x;
    const int chg = gid & (NCHG - 1);
    const int chunk = gid >> 13;
    const int dir = chg >> 12;
    const int bd = chg & 4095;
    const int b = bd >> 11, d = bd & 2047;
    const float* delta = dir ? delta1 : delta0;
    unsigned short* ub = dir ? ub1 : ub0;
    const float* xdbl = dir ? xdbl1 : xdbl0;
    const float* Alog = dir ? Alog1 : Alog0;
    const float* Dsk = dir ? Dsk1 : Dsk0;
    const float* xz = dir ? xz1 : xz0;

    float Av[16], h[16];
    const float* ph = hin + (size_t)chunk * (NCHG * 16) + (size_t)chg * 16;
    #pragma unroll
    for (int n = 0; n < 16; ++n) {
        Av[n] = -__expf(Alog[d * D_STATE + n]);
        h[n] = ph[n];
    }
    const float Dv = Dsk[d];
    const int t0 = chunk * CLEN;
    for (int t = t0; t < t0 + CLEN; ++t) {
        const size_t r = (size_t)b * SEQLEN + t;
        float dlt = delta[r * D_INNER + d];
        float uu = us2f(ub[r * 4096 + d]) + us2f(ub[r * 4096 + 2048 + d]);
        float du = dlt * uu;
        float4 bq[4], cq[4];
        #pragma unroll
        for (int q = 0; q < 4; ++q) {
            bq[q] = *(const float4*)(xdbl + r * XDBL_LD + DT_RANK + q * 4);
            cq[q] = *(const float4*)(xdbl + r * XDBL_LD + DT_RANK + D_STATE + q * 4);
        }
        float p0 = 0.f, p1 = 0.f, p2 = 0.f, p3 = 0.f;
        #pragma unroll
        for (int n = 0; n < 16; ++n) {
            float Bv = ((const float*)&bq[n >> 2])[n & 3];
            float Cv = ((const float*)&cq[n >> 2])[n & 3];
            float dA = __expf(dlt * Av[n]);
            h[n] = h[n] * dA + du * Bv;
            if ((n & 3) == 0) p0 += h[n] * Cv;
            else if ((n & 3) == 1) p1 += h[n] * Cv;
            else if ((n & 3) == 2) p2 += h[n] * Cv;
            else p3 += h[n] * Cv;
        }
        float y = ((p0 + p1) + (p2 + p3)) + uu * Dv;
        float zv = xz[r * (2 * D_INNER) + D_INNER + d];
        float v = y * (zv * sigmoidf_(zv));
        unsigned short hh, ll;
        hl_split(v, hh, ll);
        ub[r * 4096 + d] = hh;
        ub[r * 4096 + 2048 + d] = ll;
    }
}

// ---------------------------------------------------------------------------
extern "C" void kernel_launch(void* const* d_in, const int* in_sizes, int n_in,
                              void* d_out, int out_size, void* d_ws, size_t ws_size,
                              hipStream_t stream)
{
    const float* x = (const float*)d_in[0];
    const float* proj_W = (const float*)d_in[23];
    const float* proj_b = (const float*)d_in[24];
    float* out = (float*)d_out;

    const float *Win[2], *bin_[2], *convw[2], *convb[2], *Wx[2], *Wdt[2], *bdt[2],
                *Alog[2], *Dsk[2], *Wout[2], *bout[2];
    for (int dir = 0; dir < 2; ++dir) {
        const int base = 1 + dir * 11;
        Win[dir]   = (const float*)d_in[base + 0];
        bin_[dir]  = (const float*)d_in[base + 1];
        convw[dir] = (const float*)d_in[base + 2];
        convb[dir] = (const float*)d_in[base + 3];
        Wx[dir]    = (const float*)d_in[base + 4];
        Wdt[dir]   = (const float*)d_in[base + 5];
        bdt[dir]   = (const float*)d_in[base + 6];
        Alog[dir]  = (const float*)d_in[base + 7];
        Dsk[dir]   = (const float*)d_in[base + 8];
        Wout[dir]  = (const float*)d_in[base + 9];
        bout[dir]  = (const float*)d_in[base + 10];
    }

    // ---- explicit arena (lifetime-checked overlays) ----
    char* ws = (char*)d_ws;
    const size_t MB = 1ull << 20;
    float* xz[2]            = {(float*)(ws + 0 * MB),   (float*)(ws + 32 * MB)};   // [0,64)
    unsigned short* ub[2]   = {(unsigned short*)(ws + 64 * MB),
                               (unsigned short*)(ws + 80 * MB)};                   // [64,96)
    unsigned short* Winb[2] = {(unsigned short*)(ws + 96 * MB),
                               (unsigned short*)(ws + 112 * MB)};                  // [96,128)
    unsigned short* xc0     = (unsigned short*)(ws + 128 * MB);                    // [128,136)
    // overlays:
    float* part             = (float*)(ws + 112 * MB);          // xproj partials after inproj
    float* delta[2]         = {(float*)(ws + 112 * MB), (float*)(ws + 128 * MB)};
    unsigned short* Woutb[2]= {(unsigned short*)(ws + 96 * MB),
                               (unsigned short*)(ws + 104 * MB)};                  // in Winb0
    unsigned short* yzb[2]  = {ub[0], ub[1]};                   // in-place scan3
    unsigned short* tmpb    = (unsigned short*)(ws + 0 * MB);   // after scan3 (xz dead)
    unsigned short* pWb     = ub[1];                            // after out-proj
    // smalls [144,150):
    unsigned short* Wxb[2]  = {(unsigned short*)(ws + 144 * MB), (unsigned short*)(ws + 145 * MB)};
    unsigned short* Wdtb[2] = {(unsigned short*)(ws + 146 * MB), (unsigned short*)(ws + 146 * MB + 512 * 1024)};
    unsigned short* dtb[2]  = {(unsigned short*)(ws + 147 * MB), (unsigned short*)(ws + 147 * MB + 512 * 1024)};
    float* xdbl[2]          = {(float*)(ws + 148 * MB), (float*)(ws + 149 * MB)};
    // scan buffers [150,184)
    float* aprod            = (float*)(ws + 150 * MB);          // becomes hin in phase2
    float* hfin             = (float*)(ws + 167 * MB);

    dim3 blk(256);

    // 1. prep1
    prep1_kernel<<<11008, blk, 0, stream>>>(
        x, Win[0], Win[1], Wx[0], Wx[1], Wdt[0], Wdt[1],
        xc0, Winb[0], Winb[1], Wxb[0], Wxb[1], Wdtb[0], Wdtb[1]);

    // 2. input proj (8-phase 256², DUALN, SEGS=2)
    gemm256<16, true, 2><<<dim3(32, 8, 1), dim3(512), 0, stream>>>(
        xc0, nullptr, Winb[0], Winb[1], bin_[0], bin_[1], xz[0], xz[1],
        4096, 8192, D_MODEL);

    // 3. conv + silu (z=0,1) and Wout hi-only splits (z=2)
    conv_prep_kernel<<<dim3((MROWS * D_INNER) / 256, 1, 3), blk, 0, stream>>>(
        xz[0], xz[1], convw[0], convw[1], convb[0], convb[1], ub[0], ub[1],
        Wout[0], Wout[1], Woutb[0], Woutb[1]);

    // 4. xproj split-K (128² 2-barrier, 3-seg, nks=16, both dirs) -> part
    gemm_mfma<0, true><<<dim3(1, 16, 32), blk, 0, stream>>>(
        ub[0], ub[1], Wxb[0], Wxb[1], nullptr, nullptr, nullptr, nullptr,
        part, XDBL_LD, XDBL_LD, D_INNER, 16);

    // 5. reduce -> xdbl fp32 + dtb hi/lo
    reduce_xdbl_k<<<dim3(256, 1, 2), blk, 0, stream>>>(
        part, xdbl[0], xdbl[1], dtb[0], dtb[1]);

    // 6. dt proj (128² 2-barrier, 3-seg, both dirs)
    gemm_mfma<1, false><<<dim3(16, 16, 2), blk, 0, stream>>>(
        dtb[0], dtb[1], Wdtb[0], Wdtb[1], bdt[0], bdt[1], delta[0], delta[1],
        nullptr, D_INNER, D_INNER, DT_RANK, 1);

    // 7-9. chunked scan (thread-per-channel)
    scan_phase1<<<NCHUNK * NCHG / 256, blk, 0, stream>>>(
        delta[0], delta[1], ub[0], ub[1], xdbl[0], xdbl[1], Alog[0], Alog[1],
        aprod, hfin);
    scan_phase2<<<NCHG * 16 / 256, blk, 0, stream>>>(aprod, hfin);
    scan_phase3<<<NCHUNK * NCHG / 256, blk, 0, stream>>>(
        delta[0], delta[1], ub[0], ub[1], xdbl[0], xdbl[1], Alog[0], Alog[1],
        Dsk[0], Dsk[1], xz[0], xz[1], aprod);

    // 10. out proj (128² pipelined, SEGS=2, direct TMPB epilogue) -> tmpb@ws+0
    gemm128p<2, 32, 2><<<dim3(8, 16, 2), blk, 0, stream>>>(
        yzb[0], yzb[1], Woutb[0], Woutb[1], bout[0], bout[1],
        nullptr, tmpb, 0, D_INNER);

    // 11. proj_W hi-only split (ub[1] dead after out-proj)
    pwsplit_kernel<<<2048, blk, 0, stream>>>(proj_W, pWb);

    // 12. final proj (128² pipelined, SEGS=2, direct fp32 epilogue) -> out
    gemm128p<0, 32, 2><<<dim3(8, 16, 1), blk, 0, stream>>>(
        tmpb, nullptr, pWb, nullptr, proj_b, nullptr,
        out, nullptr, D_MODEL, 2 * D_MODEL);
}

// Round 18
// 400.951 us; speedup vs baseline: 1.0719x; 1.0719x over previous
//
#include <hip/hip_runtime.h>
#include <math.h>

#define D_MODEL 1024
#define D_STATE 16
#define D_CONV  4
#define D_INNER 2048
#define DT_RANK 64
#define BATCH   2
#define SEQLEN  1024
#define MROWS   2048
#define XDBL_LD 128
#define NCHUNK  32
#define CLEN    (SEQLEN / NCHUNK)   // 32
#define NCHG    8192                // 2 dirs * BATCH * D_INNER

typedef __attribute__((ext_vector_type(8))) short bf16x8;
typedef __attribute__((ext_vector_type(4))) float f32x4;

#define BARR() asm volatile("s_barrier" ::: "memory")
#define VMW(n) asm volatile("s_waitcnt vmcnt(" #n ")" ::: "memory")
#define LGKM(n) asm volatile("s_waitcnt lgkmcnt(" #n ")" ::: "memory")
#define SCHB() __builtin_amdgcn_sched_barrier(0)

static __device__ __forceinline__ float sigmoidf_(float x) {
    return 1.f / (1.f + __expf(-x));
}
static __device__ __forceinline__ unsigned short bf16rn(float f) {
    unsigned u = __float_as_uint(f);
    return (unsigned short)((u + 0x7FFFu + ((u >> 16) & 1u)) >> 16);
}
static __device__ __forceinline__ void hl_split(float f, unsigned short& h, unsigned short& l) {
    h = bf16rn(f);
    l = bf16rn(f - __uint_as_float((unsigned)h << 16));
}
static __device__ __forceinline__ float us2f(unsigned short u) {
    return __uint_as_float((unsigned)u << 16);
}

// ---------------------------------------------------------------------------
// Shared split worker: fp32 (R x C) -> bf16 (Rout x 2C) hi|lo.
// ---------------------------------------------------------------------------
static __device__ __forceinline__
void split_block(const float* __restrict__ in, int R, int C, int ldin,
                 unsigned short* __restrict__ out, int Rout, bool flip,
                 int blk, int tid)
{
    int q = blk * 256 + tid;
    int qpr = C >> 2;
    int row = q / qpr;
    int c4 = (q - row * qpr) << 2;
    if (row >= Rout) return;
    unsigned short h[4] = {0, 0, 0, 0}, l[4] = {0, 0, 0, 0};
    if (row < R) {
        int sr = row;
        if (flip) { int b = row >> 10, t = row & 1023; sr = (b << 10) + (1023 - t); }
        float4 v = *(const float4*)(in + (size_t)sr * ldin + c4);
        float f[4] = {v.x, v.y, v.z, v.w};
        #pragma unroll
        for (int i = 0; i < 4; ++i) hl_split(f[i], h[i], l[i]);
    }
    size_t ob = (size_t)row * (2 * C);
    *(ushort4*)(out + ob + c4)     = make_ushort4(h[0], h[1], h[2], h[3]);
    *(ushort4*)(out + ob + C + c4) = make_ushort4(l[0], l[1], l[2], l[3]);
}

// prep1: all pre-GEMM conversions in one launch.
__global__ __launch_bounds__(256)
void prep1_kernel(const float* __restrict__ x,
                  const float* __restrict__ Win0, const float* __restrict__ Win1,
                  const float* __restrict__ Wx0,  const float* __restrict__ Wx1,
                  const float* __restrict__ Wdt0, const float* __restrict__ Wdt1,
                  unsigned short* xc0,
                  unsigned short* Winb0, unsigned short* Winb1,
                  unsigned short* Wxb0, unsigned short* Wxb1,
                  unsigned short* Wdtb0, unsigned short* Wdtb1)
{
    int b = blockIdx.x, tid = threadIdx.x;
    if      (b < 2048)  split_block(x,    MROWS, D_MODEL, D_MODEL, xc0,  MROWS, false, b,        tid);
    else if (b < 6144)  split_block(Win0, 4096,  D_MODEL, D_MODEL, Winb0, 4096, false, b - 2048, tid);
    else if (b < 10240) split_block(Win1, 4096,  D_MODEL, D_MODEL, Winb1, 4096, false, b - 6144, tid);
    else if (b < 10496) split_block(Wx0,  96,    D_INNER, D_INNER, Wxb0,  128,  false, b - 10240, tid);
    else if (b < 10752) split_block(Wx1,  96,    D_INNER, D_INNER, Wxb1,  128,  false, b - 10496, tid);
    else if (b < 10880) split_block(Wdt0, D_INNER, DT_RANK, DT_RANK, Wdtb0, D_INNER, false, b - 10752, tid);
    else                split_block(Wdt1, D_INNER, DT_RANK, DT_RANK, Wdtb1, D_INNER, false, b - 10880, tid);
}

// ---------------------------------------------------------------------------
// 256x256 8-phase bf16x3/x2 MFMA GEMM — r13 schedule, r15 mapping, r16 SEGS.
// SEGS=3: AhiWhi + AloWhi + AhiWlo (fp32-accurate). SEGS=2: drops AhiWlo
// (error <= 2^-9 relative; used for the 3 big projections where the output
// threshold has ~4x margin).
// ---------------------------------------------------------------------------
#define SWZ(row) (((row) >> 1) & 3)
#define RDA(p, kk, row) (*(const bf16x8*)&AS[p][kk][row][(fs ^ SWZ(row)) << 3])
#define RDB(p, kk, row) (*(const bf16x8*)&BS[p][kk][row][(fs ^ SWZ(row)) << 3])

#define MFMA16(ACCBASE, AF, BF) \
    _Pragma("unroll") for (int f = 0; f < 4; ++f) \
    _Pragma("unroll") for (int g = 0; g < 4; ++g) \
        acc[(ACCBASE) + f][g] = __builtin_amdgcn_mfma_f32_16x16x32_bf16(AF[f], BF[g], acc[(ACCBASE) + f][g], 0, 0, 0);

#define KTILE(MODE, kt) do { \
    const int p_ = (kt) & 1; \
    const int pn_ = ((kt) + 1) & 1; \
    { /* P1: MFMA m0*kk0 (aFA,bFA); prefetch aFB = m1,kk0 */ \
        if (MODE < 2) stageA((kt) + 1, 1); \
        BARR(); \
        _Pragma("unroll") for (int f = 0; f < 4; ++f) { int rw = wm + 64 + f * 16 + fr; aFB[f] = RDA(p_, 0, rw); } \
        LGKM(4); SCHB(); \
        __builtin_amdgcn_s_setprio(1); \
        MFMA16(0, aFA, bFA) \
        __builtin_amdgcn_s_setprio(0); \
    } \
    { /* P2: MFMA m1*kk0 (aFB,bFA); prefetch aFA = m0,kk1 + bFB = kk1 */ \
        if (MODE == 0) stageB((kt) + 2, 0); \
        BARR(); \
        _Pragma("unroll") for (int f = 0; f < 4; ++f) { int rw = wm + f * 16 + fr; aFA[f] = RDA(p_, 1, rw); } \
        _Pragma("unroll") for (int g = 0; g < 4; ++g) { int rw = wn + g * 16 + fr; bFB[g] = RDB(p_, 1, rw); } \
        LGKM(8); SCHB(); \
        __builtin_amdgcn_s_setprio(1); \
        MFMA16(4, aFB, bFA) \
        __builtin_amdgcn_s_setprio(0); \
    } \
    { /* P3: MFMA m0*kk1 (aFA,bFB); prefetch aFB = m1,kk1 */ \
        if (MODE == 0) stageA((kt) + 2, 0); \
        BARR(); \
        _Pragma("unroll") for (int f = 0; f < 4; ++f) { int rw = wm + 64 + f * 16 + fr; aFB[f] = RDA(p_, 1, rw); } \
        LGKM(4); SCHB(); \
        __builtin_amdgcn_s_setprio(1); \
        MFMA16(0, aFA, bFB) \
        __builtin_amdgcn_s_setprio(0); \
    } \
    { /* P4: MFMA m1*kk1 (aFB,bFB); prefetch aFA,bFA = next tile kk0 */ \
        if (MODE == 0) { VMW(4); } else if (MODE == 1) { VMW(0); } \
        if (MODE == 0) stageB((kt) + 2, 1); \
        BARR(); \
        if (MODE < 2) { \
            _Pragma("unroll") for (int f = 0; f < 4; ++f) { int rw = wm + f * 16 + fr; aFA[f] = RDA(pn_, 0, rw); } \
            _Pragma("unroll") for (int g = 0; g < 4; ++g) { int rw = wn + g * 16 + fr; bFA[g] = RDB(pn_, 0, rw); } \
            LGKM(8); \
        } else { LGKM(0); } \
        SCHB(); \
        __builtin_amdgcn_s_setprio(1); \
        MFMA16(4, aFB, bFB) \
        __builtin_amdgcn_s_setprio(0); \
    } \
} while (0)

template<int ACT, bool PART, int KTS, bool DUALN, int SEGS>
__global__ __launch_bounds__(512, 1)
void gemm256(const unsigned short* __restrict__ A0,
             const unsigned short* __restrict__ A1,
             const unsigned short* __restrict__ W0,
             const unsigned short* __restrict__ W1,
             const float* __restrict__ bias0,
             const float* __restrict__ bias1,
             float* __restrict__ C0, float* __restrict__ C1,
             float* __restrict__ part,
             int ldc, int N, int K, int nks)
{
    __shared__ unsigned short AS[2][2][256][32];
    __shared__ unsigned short BS[2][2][256][32];

    const int tid = threadIdx.x;
    const int lane = tid & 63;
    const int wid = tid >> 6;

    const int z = blockIdx.z;
    const int zdir = z / nks;
    const int ks = z - zdir * nks;

    const int nbx = gridDim.x;
    const int nby = gridDim.y;
    const int nwg = nbx * nby;
    int bid = blockIdx.y * nbx + blockIdx.x;
    int q8 = nwg >> 3;
    int swz = (bid & 7) * q8 + (bid >> 3);
    // col-major mapping: row index fastest within an XCD strip (r15)
    const int bm = (swz % nby) * 256;
    const int bn = (swz / nby) * 256;

    int dn, bnn;
    if (DUALN) { dn = (bn >= (N >> 1)) ? 1 : 0; bnn = bn - dn * (N >> 1); }
    else       { dn = zdir; bnn = bn; }
    const unsigned short* A = (DUALN || dn == 0) ? A0 : A1;
    const unsigned short* W = dn ? W1 : W0;

    const int ldg = 2 * K;
    constexpr int NT = SEGS * KTS;
    const int Kc = KTS * 64;
    const int kbase = ks * Kc;

    const int wm = (wid >> 2) * 128;
    const int wn = (wid & 3) * 64;
    const int fr = lane & 15;
    const int fs = lane >> 4;

    f32x4 acc[8][4];
    #pragma unroll
    for (int i = 0; i < 8; ++i)
        #pragma unroll
        for (int j = 0; j < 4; ++j) {
            f32x4 zv = {0.f, 0.f, 0.f, 0.f};
            acc[i][j] = zv;
        }

    auto koffA = [&](int t) { unsigned tu = (unsigned)t; unsigned sg = tu / KTS;
                              unsigned w = tu - sg * KTS;
                              return (int)((sg == 1 ? (unsigned)K : 0u) + kbase + w * 64); };
    auto koffB = [&](int t) { unsigned tu = (unsigned)t; unsigned sg = tu / KTS;
                              unsigned w = tu - sg * KTS;
                              return (int)((sg == 2 ? (unsigned)K : 0u) + kbase + w * 64); };

    auto stageA = [&](int t, int kk) {
        int ko = koffA(t) + kk * 32;
        unsigned short* dst = &AS[t & 1][kk][0][0];
        #pragma unroll
        for (int i = 0; i < 2; ++i) {
            int s = i * 512 + tid;
            int row = s >> 2, sl = s & 3, lsl = sl ^ SWZ(row);
            const unsigned short* src = A + (size_t)(bm + row) * ldg + ko + lsl * 8;
            __builtin_amdgcn_global_load_lds(
                (const __attribute__((address_space(1))) void*)src,
                (__attribute__((address_space(3))) void*)(dst + s * 8), 16, 0, 0);
        }
    };
    auto stageB = [&](int t, int kk) {
        int ko = koffB(t) + kk * 32;
        unsigned short* dst = &BS[t & 1][kk][0][0];
        #pragma unroll
        for (int i = 0; i < 2; ++i) {
            int s = i * 512 + tid;
            int row = s >> 2, sl = s & 3, lsl = sl ^ SWZ(row);
            const unsigned short* src = W + (size_t)(bnn + row) * ldg + ko + lsl * 8;
            __builtin_amdgcn_global_load_lds(
                (const __attribute__((address_space(1))) void*)src,
                (__attribute__((address_space(3))) void*)(dst + s * 8), 16, 0, 0);
        }
    };

    // prologue: 7 half-tiles (K-tile 0 complete + 3/4 of K-tile 1)
    stageB(0, 0); stageA(0, 0); stageB(0, 1); stageA(0, 1);
    stageB(1, 0); stageA(1, 0); stageB(1, 1);
    VMW(6);
    BARR();

    bf16x8 aFA[4], aFB[4], bFA[4], bFB[4];
    #pragma unroll
    for (int f = 0; f < 4; ++f) { int rw = wm + f * 16 + fr; aFA[f] = RDA(0, 0, rw); }
    #pragma unroll
    for (int g = 0; g < 4; ++g) { int rw = wn + g * 16 + fr; bFA[g] = RDB(0, 0, rw); }

    #pragma unroll 1
    for (int kt = 0; kt < NT - 2; ++kt) KTILE(0, kt);
    KTILE(1, NT - 2);
    KTILE(2, NT - 1);

    if (PART) {
        float* P = part + (size_t)z * ((size_t)MROWS * N);
        #pragma unroll
        for (int i = 0; i < 8; ++i)
            #pragma unroll
            for (int j = 0; j < 4; ++j) {
                int coln = bnn + wn + j * 16 + fr;
                #pragma unroll
                for (int r = 0; r < 4; ++r) {
                    int rowm = bm + wm + i * 16 + fs * 4 + r;
                    P[(size_t)rowm * N + coln] = acc[i][j][r];
                }
            }
    } else {
        const float* bias = dn ? bias1 : bias0;
        float* C = dn ? C1 : C0;
        #pragma unroll
        for (int i = 0; i < 8; ++i)
            #pragma unroll
            for (int j = 0; j < 4; ++j) {
                int coln = bnn + wn + j * 16 + fr;
                float bv = bias ? bias[coln] : 0.f;
                #pragma unroll
                for (int r = 0; r < 4; ++r) {
                    int rowm = bm + wm + i * 16 + fs * 4 + r;
                    float v = acc[i][j][r] + bv;
                    if (ACT == 1) v = (v > 20.f) ? v : log1pf(__expf(v));
                    int crow = rowm;
                    if (DUALN && dn) { int bb = rowm >> 10, t = rowm & 1023; crow = (bb << 10) + 1023 - t; }
                    C[(size_t)crow * ldc + coln] = v;
                }
            }
    }
}

// ---------------------------------------------------------------------------
// 128x128 bf16x3 MFMA GEMM (2-barrier) for small shapes (xproj/dt) — 3-seg.
// ---------------------------------------------------------------------------
template<int ACT, bool PART>
__global__ __launch_bounds__(256)
void gemm_mfma(const unsigned short* __restrict__ A0,
               const unsigned short* __restrict__ A1,
               const unsigned short* __restrict__ W0,
               const unsigned short* __restrict__ W1,
               const float* __restrict__ bias0,
               const float* __restrict__ bias1,
               float* __restrict__ C0, float* __restrict__ C1,
               float* __restrict__ part,
               int ldc, int N, int K, int nks)
{
    __shared__ __align__(16) unsigned short As[128 * 32];
    __shared__ __align__(16) unsigned short Bs[128 * 32];

    const int tid = threadIdx.x;
    const int lane = tid & 63;
    const int wid = tid >> 6;

    const int z = blockIdx.z;
    const int dir = z / nks;
    const int ks = z - dir * nks;
    const unsigned short* A = dir ? A1 : A0;
    const unsigned short* W = dir ? W1 : W0;

    const int nbx = gridDim.x;
    const int nwg = nbx * gridDim.y;
    int bid = blockIdx.y * nbx + blockIdx.x;
    int q8 = nwg >> 3;
    int swz = (nwg >= 8) ? (bid & 7) * q8 + (bid >> 3) : bid;
    const int bm = (swz / nbx) * 128;
    const int bn = (swz % nbx) * 128;

    const int ldg = 2 * K;
    const int Kc = K / nks;
    const int kbase = ks * Kc;

    f32x4 acc[4][4];
    #pragma unroll
    for (int i = 0; i < 4; ++i)
        #pragma unroll
        for (int j = 0; j < 4; ++j) {
            f32x4 zv = {0.f, 0.f, 0.f, 0.f};
            acc[i][j] = zv;
        }

    const int r0 = tid >> 2;
    const int k0s = (tid & 3) ^ ((r0 >> 1) & 3);
    const int r1 = (256 + tid) >> 2;
    const int k1s = (tid & 3) ^ ((r1 >> 1) & 3);

    unsigned short* As_w0 = &As[(wid << 6) * 8];
    unsigned short* As_w1 = &As[(256 + (wid << 6)) * 8];
    unsigned short* Bs_w0 = &Bs[(wid << 6) * 8];
    unsigned short* Bs_w1 = &Bs[(256 + (wid << 6)) * 8];

    const int wm = (wid >> 1) * 64;
    const int wn = (wid & 1) * 64;
    const int fr = lane & 15;
    const int fs = lane >> 4;

    const int KS = Kc >> 5;
    #pragma unroll 1
    for (int seg = 0; seg < 3; ++seg) {
        const int aoff = ((seg == 1) ? K : 0) + kbase;
        const int boff = ((seg == 2) ? K : 0) + kbase;
        #pragma unroll 1
        for (int kt = 0; kt < KS; ++kt) {
            const int kk = kt << 5;
            const unsigned short* ga0 = A + (size_t)(bm + r0) * ldg + aoff + kk + k0s * 8;
            const unsigned short* ga1 = A + (size_t)(bm + r1) * ldg + aoff + kk + k1s * 8;
            const unsigned short* gw0 = W + (size_t)(bn + r0) * ldg + boff + kk + k0s * 8;
            const unsigned short* gw1 = W + (size_t)(bn + r1) * ldg + boff + kk + k1s * 8;
            __builtin_amdgcn_global_load_lds(
                (const __attribute__((address_space(1))) void*)ga0,
                (__attribute__((address_space(3))) void*)As_w0, 16, 0, 0);
            __builtin_amdgcn_global_load_lds(
                (const __attribute__((address_space(1))) void*)ga1,
                (__attribute__((address_space(3))) void*)As_w1, 16, 0, 0);
            __builtin_amdgcn_global_load_lds(
                (const __attribute__((address_space(1))) void*)gw0,
                (__attribute__((address_space(3))) void*)Bs_w0, 16, 0, 0);
            __builtin_amdgcn_global_load_lds(
                (const __attribute__((address_space(1))) void*)gw1,
                (__attribute__((address_space(3))) void*)Bs_w1, 16, 0, 0);
            __syncthreads();

            bf16x8 aF[4], bF[4];
            #pragma unroll
            for (int f = 0; f < 4; ++f) {
                int ra = wm + f * 16 + fr;
                int sa = fs ^ ((ra >> 1) & 3);
                aF[f] = *(const bf16x8*)&As[ra * 32 + sa * 8];
                int rb = wn + f * 16 + fr;
                int sb = fs ^ ((rb >> 1) & 3);
                bF[f] = *(const bf16x8*)&Bs[rb * 32 + sb * 8];
            }
            #pragma unroll
            for (int i = 0; i < 4; ++i)
                #pragma unroll
                for (int j = 0; j < 4; ++j)
                    acc[i][j] = __builtin_amdgcn_mfma_f32_16x16x32_bf16(
                        aF[i], bF[j], acc[i][j], 0, 0, 0);
            __syncthreads();
        }
    }

    if (PART) {
        float* P = part + (size_t)z * ((size_t)MROWS * N);
        #pragma unroll
        for (int i = 0; i < 4; ++i)
            #pragma unroll
            for (int j = 0; j < 4; ++j) {
                int coln = bn + wn + j * 16 + fr;
                #pragma unroll
                for (int r = 0; r < 4; ++r) {
                    int rowm = bm + wm + i * 16 + fs * 4 + r;
                    P[(size_t)rowm * N + coln] = acc[i][j][r];
                }
            }
    } else {
        const float* bias = dir ? bias1 : bias0;
        float* C = dir ? C1 : C0;
        #pragma unroll
        for (int i = 0; i < 4; ++i)
            #pragma unroll
            for (int j = 0; j < 4; ++j) {
                int coln = bn + wn + j * 16 + fr;
                float bv = bias ? bias[coln] : 0.f;
                #pragma unroll
                for (int r = 0; r < 4; ++r) {
                    int rowm = bm + wm + i * 16 + fs * 4 + r;
                    float v = acc[i][j][r] + bv;
                    if (ACT == 1) v = (v > 20.f) ? v : log1pf(__expf(v));
                    C[(size_t)rowm * ldc + coln] = v;
                }
            }
    }
}

// ---------------------------------------------------------------------------
// Split-K reduces with fused epilogues (z-batched over dir).
// ---------------------------------------------------------------------------
__global__ __launch_bounds__(256)
void reduce_xdbl_k(const float* __restrict__ part,
                   float* __restrict__ xdbl0, float* __restrict__ xdbl1,
                   unsigned short* __restrict__ dtb0, unsigned short* __restrict__ dtb1)
{
    const int dz = blockIdx.z;
    const float* P = part + (size_t)dz * 16 * MROWS * XDBL_LD;
    float* xdbl = dz ? xdbl1 : xdbl0;
    unsigned short* dtb = dz ? dtb1 : dtb0;
    int i = blockIdx.x * 256 + threadIdx.x;
    int row = i >> 5;
    int c4 = (i & 31) << 2;
    float4 s = make_float4(0.f, 0.f, 0.f, 0.f);
    #pragma unroll
    for (int k = 0; k < 16; ++k) {
        float4 v = *(const float4*)(P + (size_t)k * MROWS * XDBL_LD + (size_t)row * XDBL_LD + c4);
        s.x += v.x; s.y += v.y; s.z += v.z; s.w += v.w;
    }
    *(float4*)(xdbl + (size_t)row * XDBL_LD + c4) = s;
    if (c4 < DT_RANK) {
        float f[4] = {s.x, s.y, s.z, s.w};
        unsigned short h[4], l[4];
        #pragma unroll
        for (int j = 0; j < 4; ++j) hl_split(f[j], h[j], l[j]);
        *(ushort4*)(dtb + (size_t)row * (2 * DT_RANK) + c4) = make_ushort4(h[0], h[1], h[2], h[3]);
        *(ushort4*)(dtb + (size_t)row * (2 * DT_RANK) + DT_RANK + c4) = make_ushort4(l[0], l[1], l[2], l[3]);
    }
}

// mid: z=0/1 -> reduce out-proj partials (4/dir) + bias + flip -> tmpb; z=2 -> proj_W split.
__global__ __launch_bounds__(256)
void mid_kernel(const float* __restrict__ part2,
                const float* __restrict__ bout0, const float* __restrict__ bout1,
                unsigned short* __restrict__ tmpb,
                const float* __restrict__ projW, unsigned short* __restrict__ pWb)
{
    const int dz = blockIdx.z;
    const int tid = threadIdx.x;
    if (dz == 2) {
        split_block(projW, D_MODEL, 2 * D_MODEL, 2 * D_MODEL, pWb, D_MODEL, false, blockIdx.x, tid);
        return;
    }
    const float* P = part2 + (size_t)dz * 4 * MROWS * D_MODEL;
    const float* bias = dz ? bout1 : bout0;
    const int colofs = dz ? D_MODEL : 0;
    int i = blockIdx.x * 256 + tid;
    int row = i >> 8;
    int c4 = (i & 255) << 2;
    float4 s = make_float4(bias[c4], bias[c4 + 1], bias[c4 + 2], bias[c4 + 3]);
    #pragma unroll
    for (int k = 0; k < 4; ++k) {
        float4 v = *(const float4*)(P + (size_t)k * MROWS * D_MODEL + (size_t)row * D_MODEL + c4);
        s.x += v.x; s.y += v.y; s.z += v.z; s.w += v.w;
    }
    int orow = row;
    if (dz) { int bb = row >> 10, t = row & 1023; orow = (bb << 10) + 1023 - t; }
    float f[4] = {s.x, s.y, s.z, s.w};
    unsigned short h[4], l[4];
    #pragma unroll
    for (int j = 0; j < 4; ++j) hl_split(f[j], h[j], l[j]);
    *(ushort4*)(tmpb + (size_t)orow * 4096 + colofs + c4) = make_ushort4(h[0], h[1], h[2], h[3]);
    *(ushort4*)(tmpb + (size_t)orow * 4096 + 2048 + colofs + c4) = make_ushort4(l[0], l[1], l[2], l[3]);
}

__global__ __launch_bounds__(256)
void reduce_out_k(const float* __restrict__ part, const float* __restrict__ bias,
                  float* __restrict__ out)
{
    int i = blockIdx.x * 256 + threadIdx.x;
    int row = i >> 8;
    int c4 = (i & 255) << 2;
    float4 s = make_float4(bias[c4], bias[c4 + 1], bias[c4 + 2], bias[c4 + 3]);
    #pragma unroll
    for (int k = 0; k < 8; ++k) {
        float4 v = *(const float4*)(part + (size_t)k * MROWS * D_MODEL + (size_t)row * D_MODEL + c4);
        s.x += v.x; s.y += v.y; s.z += v.z; s.w += v.w;
    }
    *(float4*)(out + (size_t)row * D_MODEL + c4) = s;
}

// ---------------------------------------------------------------------------
// conv+prep2: z=0/1 -> causal conv + SiLU -> ub hi/lo; z=2 -> Wout splits.
// ---------------------------------------------------------------------------
__global__ __launch_bounds__(256)
void conv_prep_kernel(const float* __restrict__ xz0, const float* __restrict__ xz1,
                      const float* __restrict__ cw0, const float* __restrict__ cw1,
                      const float* __restrict__ cb0, const float* __restrict__ cb1,
                      unsigned short* __restrict__ ub0, unsigned short* __restrict__ ub1,
                      const float* __restrict__ Wout0, const float* __restrict__ Wout1,
                      unsigned short* __restrict__ Woutb0, unsigned short* __restrict__ Woutb1)
{
    const int dz = blockIdx.z;
    const int tid = threadIdx.x;
    if (dz == 2) {
        int b = blockIdx.x;
        if (b < 2048) split_block(Wout0, D_MODEL, D_INNER, D_INNER, Woutb0, D_MODEL, false, b, tid);
        else if (b < 4096) split_block(Wout1, D_MODEL, D_INNER, D_INNER, Woutb1, D_MODEL, false, b - 2048, tid);
        return;
    }
    const float* xz = dz ? xz1 : xz0;
    const float* convw = dz ? cw1 : cw0;
    const float* convb = dz ? cb1 : cb0;
    unsigned short* ub = dz ? ub1 : ub0;
    int idx = blockIdx.x * 256 + tid;
    int d = idx % D_INNER;
    int r = idx / D_INNER;
    int t = r % SEQLEN;
    float acc = convb[d];
    #pragma unroll
    for (int k = 0; k < D_CONV; ++k) {
        int back = D_CONV - 1 - k;
        if (t - back >= 0)
            acc += xz[(size_t)(r - back) * (2 * D_INNER) + d] * convw[d * D_CONV + k];
    }
    float v = acc * sigmoidf_(acc);
    unsigned short h, l;
    hl_split(v, h, l);
    ub[(size_t)r * (2 * D_INNER) + d] = h;
    ub[(size_t)r * (2 * D_INNER) + D_INNER + d] = l;
}

// ---------------------------------------------------------------------------
// Chunked selective scan, thread-per-channel (16 states in registers).
// ---------------------------------------------------------------------------
__global__ __launch_bounds__(256)
void scan_phase1(const float* __restrict__ delta0, const float* __restrict__ delta1,
                 const unsigned short* __restrict__ ub0, const unsigned short* __restrict__ ub1,
                 const float* __restrict__ xdbl0, const float* __restrict__ xdbl1,
                 const float* __restrict__ Alog0, const float* __restrict__ Alog1,
                 float* __restrict__ aprod, float* __restrict__ hfin)
{
    const int gid = blockIdx.x * 256 + threadIdx.x;
    const int chg = gid & (NCHG - 1);
    const int chunk = gid >> 13;
    const int dir = chg >> 12;
    const int bd = chg & 4095;
    const int b = bd >> 11, d = bd & 2047;
    const float* delta = dir ? delta1 : delta0;
    const unsigned short* ub = dir ? ub1 : ub0;
    const float* xdbl = dir ? xdbl1 : xdbl0;
    const float* Alog = dir ? Alog1 : Alog0;

    float Av[16], h[16], ap[16];
    #pragma unroll
    for (int n = 0; n < 16; ++n) {
        Av[n] = -__expf(Alog[d * D_STATE + n]);
        h[n] = 0.f; ap[n] = 1.f;
    }
    const int t0 = chunk * CLEN;
    for (int t = t0; t < t0 + CLEN; ++t) {
        const size_t r = (size_t)b * SEQLEN + t;
        float dlt = delta[r * D_INNER + d];
        float uu = us2f(ub[r * 4096 + d]) + us2f(ub[r * 4096 + 2048 + d]);
        float du = dlt * uu;
        float4 bq[4];
        #pragma unroll
        for (int q = 0; q < 4; ++q)
            bq[q] = *(const float4*)(xdbl + r * XDBL_LD + DT_RANK + q * 4);
        #pragma unroll
        for (int n = 0; n < 16; ++n) {
            float Bv = ((const float*)&bq[n >> 2])[n & 3];
            float dA = __expf(dlt * Av[n]);
            h[n] = h[n] * dA + du * Bv;
            ap[n] *= dA;
        }
    }
    float* pa = aprod + (size_t)chunk * (NCHG * 16) + (size_t)chg * 16;
    float* pf = hfin  + (size_t)chunk * (NCHG * 16) + (size_t)chg * 16;
    #pragma unroll
    for (int q = 0; q < 4; ++q) {
        *(float4*)(pa + q * 4) = make_float4(ap[q*4], ap[q*4+1], ap[q*4+2], ap[q*4+3]);
        *(float4*)(pf + q * 4) = make_float4(h[q*4], h[q*4+1], h[q*4+2], h[q*4+3]);
    }
}

__global__ __launch_bounds__(256)
void scan_phase2(float* __restrict__ aprod /* in: A, out: hin */,
                 const float* __restrict__ hfin)
{
    const int gid = blockIdx.x * 256 + threadIdx.x;
    float h = 0.f;
    for (int c = 0; c < NCHUNK; ++c) {
        const size_t idx = (size_t)c * (NCHG * 16) + gid;
        float a = aprod[idx];
        float f = hfin[idx];
        aprod[idx] = h;
        h = a * h + f;
    }
}

__global__ __launch_bounds__(256)
void scan_phase3(const float* __restrict__ delta0, const float* __restrict__ delta1,
                 unsigned short* __restrict__ ub0, unsigned short* __restrict__ ub1,
                 const float* __restrict__ xdbl0, const float* __restrict__ xdbl1,
                 const float* __restrict__ Alog0, const float* __restrict__ Alog1,
                 const float* __restrict__ Dsk0, const float* __restrict__ Dsk1,
                 const float* __restrict__ xz0, const float* __restrict__ xz1,
                 const float* __restrict__ hin)
{
    const int gid = blockIdx.x * 256 + threadIdx.x;
    const int chg = gid & (NCHG - 1);
    const int chunk = gid >> 13;
    const int dir = chg >> 12;
    const int bd = chg & 4095;
    const int b = bd >> 11, d = bd & 2047;
    const float* delta = dir ? delta1 : delta0;
    unsigned short* ub = dir ? ub1 : ub0;
    const float* xdbl = dir ? xdbl1 : xdbl0;
    const float* Alog = dir ? Alog1 : Alog0;
    const float* Dsk = dir ? Dsk1 : Dsk0;
    const float* xz = dir ? xz1 : xz0;

    float Av[16], h[16];
    const float* ph = hin + (size_t)chunk * (NCHG * 16) + (size_t)chg * 16;
    #pragma unroll
    for (int n = 0; n < 16; ++n) {
        Av[n] = -__expf(Alog[d * D_STATE + n]);
        h[n] = ph[n];
    }
    const float Dv = Dsk[d];
    const int t0 = chunk * CLEN;
    for (int t = t0; t < t0 + CLEN; ++t) {
        const size_t r = (size_t)b * SEQLEN + t;
        float dlt = delta[r * D_INNER + d];
        float uu = us2f(ub[r * 4096 + d]) + us2f(ub[r * 4096 + 2048 + d]);
        float du = dlt * uu;
        float4 bq[4], cq[4];
        #pragma unroll
        for (int q = 0; q < 4; ++q) {
            bq[q] = *(const float4*)(xdbl + r * XDBL_LD + DT_RANK + q * 4);
            cq[q] = *(const float4*)(xdbl + r * XDBL_LD + DT_RANK + D_STATE + q * 4);
        }
        float p0 = 0.f, p1 = 0.f, p2 = 0.f, p3 = 0.f;
        #pragma unroll
        for (int n = 0; n < 16; ++n) {
            float Bv = ((const float*)&bq[n >> 2])[n & 3];
            float Cv = ((const float*)&cq[n >> 2])[n & 3];
            float dA = __expf(dlt * Av[n]);
            h[n] = h[n] * dA + du * Bv;
            if ((n & 3) == 0) p0 += h[n] * Cv;
            else if ((n & 3) == 1) p1 += h[n] * Cv;
            else if ((n & 3) == 2) p2 += h[n] * Cv;
            else p3 += h[n] * Cv;
        }
        float y = ((p0 + p1) + (p2 + p3)) + uu * Dv;
        float zv = xz[r * (2 * D_INNER) + D_INNER + d];
        float v = y * (zv * sigmoidf_(zv));
        unsigned short hh, ll;
        hl_split(v, hh, ll);
        ub[r * 4096 + d] = hh;
        ub[r * 4096 + 2048 + d] = ll;
    }
}

// ---------------------------------------------------------------------------
extern "C" void kernel_launch(void* const* d_in, const int* in_sizes, int n_in,
                              void* d_out, int out_size, void* d_ws, size_t ws_size,
                              hipStream_t stream)
{
    const float* x = (const float*)d_in[0];
    const float* proj_W = (const float*)d_in[23];
    const float* proj_b = (const float*)d_in[24];
    float* out = (float*)d_out;

    const float *Win[2], *bin_[2], *convw[2], *convb[2], *Wx[2], *Wdt[2], *bdt[2],
                *Alog[2], *Dsk[2], *Wout[2], *bout[2];
    for (int dir = 0; dir < 2; ++dir) {
        const int base = 1 + dir * 11;
        Win[dir]   = (const float*)d_in[base + 0];
        bin_[dir]  = (const float*)d_in[base + 1];
        convw[dir] = (const float*)d_in[base + 2];
        convb[dir] = (const float*)d_in[base + 3];
        Wx[dir]    = (const float*)d_in[base + 4];
        Wdt[dir]   = (const float*)d_in[base + 5];
        bdt[dir]   = (const float*)d_in[base + 6];
        Alog[dir]  = (const float*)d_in[base + 7];
        Dsk[dir]   = (const float*)d_in[base + 8];
        Wout[dir]  = (const float*)d_in[base + 9];
        bout[dir]  = (const float*)d_in[base + 10];
    }

    // ---- explicit arena (lifetime-checked overlays; high-water ~184 MiB) ----
    char* ws = (char*)d_ws;
    const size_t MB = 1ull << 20;
    float* xz[2]            = {(float*)(ws + 0 * MB),   (float*)(ws + 32 * MB)};   // [0,64)
    unsigned short* ub[2]   = {(unsigned short*)(ws + 64 * MB),
                               (unsigned short*)(ws + 80 * MB)};                   // [64,96)
    unsigned short* Winb[2] = {(unsigned short*)(ws + 96 * MB),
                               (unsigned short*)(ws + 112 * MB)};                  // [96,128)
    unsigned short* xc0     = (unsigned short*)(ws + 128 * MB);                    // [128,136)
    // overlays:
    float* part             = (float*)(ws + 112 * MB);          // xproj partials after inproj
    float* part2            = (float*)(ws + 0 * MB);            // after scan3 (xz dead)
    float* delta[2]         = {(float*)(ws + 112 * MB), (float*)(ws + 128 * MB)};
    unsigned short* Woutb[2]= {(unsigned short*)(ws + 96 * MB),
                               (unsigned short*)(ws + 104 * MB)};                  // in Winb0
    unsigned short* yzb[2]  = {ub[0], ub[1]};                   // in-place scan3
    unsigned short* tmpb    = ub[0];                            // after out-proj
    unsigned short* pWb     = ub[1];                            // after out-proj
    // smalls [144,150):
    unsigned short* Wxb[2]  = {(unsigned short*)(ws + 144 * MB), (unsigned short*)(ws + 145 * MB)};
    unsigned short* Wdtb[2] = {(unsigned short*)(ws + 146 * MB), (unsigned short*)(ws + 146 * MB + 512 * 1024)};
    unsigned short* dtb[2]  = {(unsigned short*)(ws + 147 * MB), (unsigned short*)(ws + 147 * MB + 512 * 1024)};
    float* xdbl[2]          = {(float*)(ws + 148 * MB), (float*)(ws + 149 * MB)};
    // scan buffers [150,184)
    float* aprod            = (float*)(ws + 150 * MB);          // becomes hin in phase2
    float* hfin             = (float*)(ws + 167 * MB);

    dim3 blk(256);

    // 1. prep1
    prep1_kernel<<<11008, blk, 0, stream>>>(
        x, Win[0], Win[1], Wx[0], Wx[1], Wdt[0], Wdt[1],
        xc0, Winb[0], Winb[1], Wxb[0], Wxb[1], Wdtb[0], Wdtb[1]);

    // 2. input proj (8-phase 256², DUALN, SEGS=2)
    gemm256<0, false, 16, true, 2><<<dim3(32, 8, 1), dim3(512), 0, stream>>>(
        xc0, nullptr, Winb[0], Winb[1], bin_[0], bin_[1], xz[0], xz[1],
        nullptr, 4096, 8192, D_MODEL, 1);

    // 3. conv + silu -> ub hi/lo (z=0,1) and Wout splits (z=2)
    conv_prep_kernel<<<dim3((MROWS * D_INNER) / 256, 1, 3), blk, 0, stream>>>(
        xz[0], xz[1], convw[0], convw[1], convb[0], convb[1], ub[0], ub[1],
        Wout[0], Wout[1], Woutb[0], Woutb[1]);

    // 4. xproj split-K (128² 2-barrier, 3-seg, nks=16, both dirs) -> part
    gemm_mfma<0, true><<<dim3(1, 16, 32), blk, 0, stream>>>(
        ub[0], ub[1], Wxb[0], Wxb[1], nullptr, nullptr, nullptr, nullptr,
        part, XDBL_LD, XDBL_LD, D_INNER, 16);

    // 5. reduce -> xdbl fp32 + dtb hi/lo
    reduce_xdbl_k<<<dim3(256, 1, 2), blk, 0, stream>>>(
        part, xdbl[0], xdbl[1], dtb[0], dtb[1]);

    // 6. dt proj (128² 2-barrier, 3-seg, both dirs)
    gemm_mfma<1, false><<<dim3(16, 16, 2), blk, 0, stream>>>(
        dtb[0], dtb[1], Wdtb[0], Wdtb[1], bdt[0], bdt[1], delta[0], delta[1],
        nullptr, D_INNER, D_INNER, DT_RANK, 1);

    // 7-9. thread-per-channel chunked scan
    scan_phase1<<<NCHUNK * NCHG / 256, blk, 0, stream>>>(
        delta[0], delta[1], ub[0], ub[1], xdbl[0], xdbl[1], Alog[0], Alog[1],
        aprod, hfin);
    scan_phase2<<<NCHG * 16 / 256, blk, 0, stream>>>(aprod, hfin);
    scan_phase3<<<NCHUNK * NCHG / 256, blk, 0, stream>>>(
        delta[0], delta[1], ub[0], ub[1], xdbl[0], xdbl[1], Alog[0], Alog[1],
        Dsk[0], Dsk[1], xz[0], xz[1], aprod);

    // 10. out proj (8-phase 256², SEGS=2, nks=4, both dirs) -> part2 [xz dead]
    gemm256<0, true, 8, false, 2><<<dim3(4, 8, 8), dim3(512), 0, stream>>>(
        yzb[0], yzb[1], Woutb[0], Woutb[1], nullptr, nullptr, nullptr, nullptr,
        part2, D_MODEL, D_MODEL, D_INNER, 4);

    // 11. mid: reduce out-proj partials (4/dir) -> tmpb + split proj_W -> pWb
    mid_kernel<<<dim3(2048, 1, 3), blk, 0, stream>>>(
        part2, bout[0], bout[1], tmpb, proj_W, pWb);

    // 12. final proj (8-phase 256², SEGS=2, nks=8) -> part2
    gemm256<0, true, 4, false, 2><<<dim3(4, 8, 8), dim3(512), 0, stream>>>(
        tmpb, nullptr, pWb, nullptr, nullptr, nullptr, nullptr, nullptr,
        part2, D_MODEL, D_MODEL, 2 * D_MODEL, 8);

    // 13. reduce -> out
    reduce_out_k<<<2048, blk, 0, stream>>>(part2, proj_b, out);
}